// Round 11
// baseline (478.701 us; speedup 1.0000x reference)
//
#include <hip/hip_runtime.h>
#include <stdint.h>
#include <stddef.h>

#define B_ 2
#define T_ 2048
#define C_ 1024
#define H_ 16
#define N_ 64
#define M_ (B_*T_)
#define L_ 128              // chunk length
#define NC_ (T_/L_)         // 16 chunks

typedef unsigned short ushort_t;
typedef __attribute__((ext_vector_type(8))) __bf16 bf16x8;
typedef __attribute__((ext_vector_type(4))) float  f32x4;

__device__ __forceinline__ ushort_t f2bf(float x){
  uint32_t u = __float_as_uint(x);
  u += 0x7fffu + ((u >> 16) & 1u);   // RNE to bf16 (inputs finite)
  return (ushort_t)(u >> 16);
}
__device__ __forceinline__ float bf2f(uint32_t hu){
  return __uint_as_float(hu << 16);
}
// sum across 4-lane quad via DPP (VALU pipe, not ds_swizzle)
__device__ __forceinline__ float quad_sum(float v){
  float a = __int_as_float(__builtin_amdgcn_mov_dpp(__float_as_int(v), 0xB1, 0xF, 0xF, true)); // xor 1
  v += a;
  float b = __int_as_float(__builtin_amdgcn_mov_dpp(__float_as_int(v), 0x4E, 0xF, 0xF, true)); // xor 2
  return v + b;
}

// ---------------- merged prep: activations + weights + missT ----------------
__device__ __forceinline__ ushort4 mixq4(float4 a, float4 p, float4 c){
  ushort4 o;
  o.x = f2bf(fmaf(p.x - a.x, c.x, a.x));
  o.y = f2bf(fmaf(p.y - a.y, c.y, a.y));
  o.z = f2bf(fmaf(p.z - a.z, c.z, a.z));
  o.w = f2bf(fmaf(p.w - a.w, c.w, a.w));
  return o;
}
__global__ __launch_bounds__(256) void prep_all(
    const float* __restrict__ x, const float* __restrict__ x0,
    const float* __restrict__ dx0,
    const float* __restrict__ xq, const float* __restrict__ xk,
    const float* __restrict__ xv,
    const float* __restrict__ Wq, const float* __restrict__ Wk,
    const float* __restrict__ Wv, const float* __restrict__ Wp,
    const float* __restrict__ miss,
    ushort_t* __restrict__ Aq, ushort_t* __restrict__ Ak,
    ushort_t* __restrict__ Av, ushort_t* __restrict__ Axf,
    ushort_t* __restrict__ Xb,
    ushort_t* __restrict__ Wb, ushort_t* __restrict__ Wpb,
    ushort_t* __restrict__ missT)
{
  __shared__ ushort_t tile[128][66];
  const int blk = blockIdx.x;
  const int tid = threadIdx.x;
  if (blk < 4096){
    const int idx = blk*256 + tid;
    const int col4 = idx & 255;
    const int i = idx >> 8;
    const int t = i & (T_-1);
    float4 a = ((const float4*)x)[idx];
    float4 p = {0.f,0.f,0.f,0.f};
    if (t > 0) p = ((const float4*)x)[idx - 256];
    float4 cq = ((const float4*)xq)[col4];
    float4 ck = ((const float4*)xk)[col4];
    float4 cv = ((const float4*)xv)[col4];
    ((ushort4*)Aq)[idx] = mixq4(a, p, cq);
    ((ushort4*)Ak)[idx] = mixq4(a, p, ck);
    ((ushort4*)Av)[idx] = mixq4(a, p, cv);
    float4 z = ((const float4*)x0)[idx];
    float4 d = ((const float4*)dx0)[idx];
    ushort4 of;
    of.x = f2bf(fmaf(d.x, cv.x, z.x));
    of.y = f2bf(fmaf(d.y, cv.y, z.y));
    of.z = f2bf(fmaf(d.z, cv.z, z.z));
    of.w = f2bf(fmaf(d.w, cv.w, z.w));
    ((ushort4*)Axf)[idx] = of;
    ushort4 ob = {f2bf(a.x), f2bf(a.y), f2bf(a.z), f2bf(a.w)};
    ((ushort4*)Xb)[idx] = ob;
  } else if (blk < 4096 + 5*1024){
    const int y = (blk - 4096) >> 10;
    const float* src = (y==0)?Wq:(y==1)?Wk:(y<4)?Wv:Wp;
    ushort_t* dst = (y<4) ? Wb + (size_t)y*C_*C_ : Wpb;
    const int idx = ((blk - 4096) & 1023)*256 + tid;
    float4 v = ((const float4*)src)[idx];
    ushort4 o = {f2bf(v.x), f2bf(v.y), f2bf(v.z), f2bf(v.w)};
    ((ushort4*)dst)[idx] = o;
  } else {
    const int j0 = (blk - 4096 - 5*1024)*64;
#pragma unroll
    for (int rep=0; rep<8; rep++){
      int k = rep*16 + (tid>>4);
      int jj = (tid&15)*4;
      float4 v = *(const float4*)&miss[(size_t)k*4096 + j0 + jj];
      tile[k][jj+0]=f2bf(v.x); tile[k][jj+1]=f2bf(v.y);
      tile[k][jj+2]=f2bf(v.z); tile[k][jj+3]=f2bf(v.w);
    }
    __syncthreads();
#pragma unroll
    for (int rep=0; rep<8; rep++){
      int j = tid>>2;
      int kk = (tid&3)*32 + rep*4;
      ushort4 o = {tile[kk+0][j], tile[kk+1][j], tile[kk+2][j], tile[kk+3][j]};
      *(ushort4*)&missT[(size_t)(j0+j)*128 + kk] = o;
    }
  }
}

// ---------------- bf16 MFMA GEMM (m97 structure), generic (out-proj) -------
__global__ __launch_bounds__(256, 2) void mfma_gemm(
    const ushort_t* __restrict__ Ab, int lda, int64_t Asz,
    const ushort_t* __restrict__ Bbp, int ldb, int64_t Bsz,
    void* __restrict__ Cb, int ldc, int64_t Csz, int c_bf16,
    const float* __restrict__ resid, int K)
{
  const ushort_t* A  = Ab  + (size_t)blockIdx.z * Asz;
  const ushort_t* Bm = Bbp + (size_t)blockIdx.z * Bsz;
  const int i0 = blockIdx.y * 128;
  const int j0 = blockIdx.x * 128;
  const int tid = threadIdx.x;
  const int lane = tid & 63;
  const int w = tid >> 6;
  const int wm = w & 1, wn = w >> 1;

  __shared__ ushort_t As[128*32];
  __shared__ ushort_t Bs[128*32];

  f32x4 acc[4][4];
#pragma unroll
  for (int i=0;i<4;i++)
#pragma unroll
    for (int j=0;j<4;j++) acc[i][j] = (f32x4){0.f,0.f,0.f,0.f};

  const int lr = lane >> 2;
  const int ls = lane & 3;
  const ushort_t* ga = A  + (size_t)(i0 + w*32 + lr)*lda + ls*8;
  const ushort_t* gb = Bm + (size_t)(j0 + w*32 + lr)*ldb + ls*8;
  const int lm = lane & 15, lq = lane >> 4;

  for (int k0 = 0; k0 < K; k0 += 32){
    __syncthreads();
#pragma unroll
    for (int p=0;p<2;p++){
      __builtin_amdgcn_global_load_lds(
        (const __attribute__((address_space(1))) void*)(ga + (size_t)p*16*lda + k0),
        (__attribute__((address_space(3))) void*)&As[(w*32 + p*16)*32], 16, 0, 0);
      __builtin_amdgcn_global_load_lds(
        (const __attribute__((address_space(1))) void*)(gb + (size_t)p*16*ldb + k0),
        (__attribute__((address_space(3))) void*)&Bs[(w*32 + p*16)*32], 16, 0, 0);
    }
    __syncthreads();
    bf16x8 af[4], bfr[4];
#pragma unroll
    for (int i=0;i<4;i++)
      af[i] = *(const bf16x8*)&As[(wm*64 + i*16 + lm)*32 + lq*8];
#pragma unroll
    for (int j=0;j<4;j++)
      bfr[j] = *(const bf16x8*)&Bs[(wn*64 + j*16 + lm)*32 + lq*8];
#pragma unroll
    for (int i=0;i<4;i++)
#pragma unroll
      for (int j=0;j<4;j++)
        acc[i][j] = __builtin_amdgcn_mfma_f32_16x16x32_bf16(af[i], bfr[j], acc[i][j], 0, 0, 0);
  }

  if (!c_bf16){
    float* C = (float*)Cb + (size_t)blockIdx.z * Csz;
#pragma unroll
    for (int i=0;i<4;i++)
#pragma unroll
      for (int j=0;j<4;j++)
#pragma unroll
        for (int r=0;r<4;r++){
          const int row = i0 + wm*64 + i*16 + lq*4 + r;
          const int col = j0 + wn*64 + j*16 + lm;
          float v = acc[i][j][r];
          if (resid) v += resid[(size_t)row*ldc + col];
          C[(size_t)row*ldc + col] = v;
        }
  } else {
    ushort_t* C = (ushort_t*)Cb + (size_t)blockIdx.z * Csz;
#pragma unroll
    for (int i=0;i<4;i++)
#pragma unroll
      for (int j=0;j<4;j++)
#pragma unroll
        for (int r=0;r<4;r++){
          const int row = i0 + wm*64 + i*16 + lq*4 + r;
          const int col = j0 + wn*64 + j*16 + lm;
          C[(size_t)row*ldc + col] = f2bf(acc[i][j][r]);
        }
  }
}

// ---------------- merged QKV (z=0..3) + miss GEMM, one launch -------------
__global__ __launch_bounds__(256, 2) void qkvm_gemm(
    const ushort_t* __restrict__ Ab4, const ushort_t* __restrict__ Wb,
    const ushort_t* __restrict__ Xb,  const ushort_t* __restrict__ missT,
    float* __restrict__ qkvf, ushort_t* __restrict__ delb)
{
  const int bid = blockIdx.x;
  const bool isQKV = bid < 1024;
  const ushort_t* A; const ushort_t* Bm;
  int i0, j0, ldb, K, z = 0;
  if (isQKV){
    z = bid >> 8;
    const int g = bid & 255;
    j0 = (g & 7) * 128;
    i0 = (g >> 3) * 128;
    A  = Ab4 + (size_t)z*M_*C_;
    Bm = Wb  + (size_t)z*C_*C_;
    ldb = C_; K = C_;
  } else {
    const int g = bid - 1024;
    j0 = (g & 31) * 128;
    i0 = (g >> 5) * 128;
    A = Xb; Bm = missT;
    ldb = 128; K = 128;
  }
  const int lda = C_;
  const int tid = threadIdx.x;
  const int lane = tid & 63;
  const int w = tid >> 6;
  const int wm = w & 1, wn = w >> 1;

  __shared__ ushort_t As[128*32];
  __shared__ ushort_t Bs[128*32];

  f32x4 acc[4][4];
#pragma unroll
  for (int i=0;i<4;i++)
#pragma unroll
    for (int j=0;j<4;j++) acc[i][j] = (f32x4){0.f,0.f,0.f,0.f};

  const int lr = lane >> 2;
  const int ls = lane & 3;
  const ushort_t* ga = A  + (size_t)(i0 + w*32 + lr)*lda + ls*8;
  const ushort_t* gb = Bm + (size_t)(j0 + w*32 + lr)*ldb + ls*8;
  const int lm = lane & 15, lq = lane >> 4;

  for (int k0 = 0; k0 < K; k0 += 32){
    __syncthreads();
#pragma unroll
    for (int p=0;p<2;p++){
      __builtin_amdgcn_global_load_lds(
        (const __attribute__((address_space(1))) void*)(ga + (size_t)p*16*lda + k0),
        (__attribute__((address_space(3))) void*)&As[(w*32 + p*16)*32], 16, 0, 0);
      __builtin_amdgcn_global_load_lds(
        (const __attribute__((address_space(1))) void*)(gb + (size_t)p*16*ldb + k0),
        (__attribute__((address_space(3))) void*)&Bs[(w*32 + p*16)*32], 16, 0, 0);
    }
    __syncthreads();
    bf16x8 af[4], bfr[4];
#pragma unroll
    for (int i=0;i<4;i++)
      af[i] = *(const bf16x8*)&As[(wm*64 + i*16 + lm)*32 + lq*8];
#pragma unroll
    for (int j=0;j<4;j++)
      bfr[j] = *(const bf16x8*)&Bs[(wn*64 + j*16 + lm)*32 + lq*8];
#pragma unroll
    for (int i=0;i<4;i++)
#pragma unroll
      for (int j=0;j<4;j++)
        acc[i][j] = __builtin_amdgcn_mfma_f32_16x16x32_bf16(af[i], bfr[j], acc[i][j], 0, 0, 0);
  }

  if (isQKV){
    float* C = qkvf + (size_t)z*M_*C_;
#pragma unroll
    for (int i=0;i<4;i++)
#pragma unroll
      for (int j=0;j<4;j++)
#pragma unroll
        for (int r=0;r<4;r++){
          const int row = i0 + wm*64 + i*16 + lq*4 + r;
          const int col = j0 + wn*64 + j*16 + lm;
          C[(size_t)row*C_ + col] = acc[i][j][r];
        }
  } else {
#pragma unroll
    for (int i=0;i<4;i++)
#pragma unroll
      for (int j=0;j<4;j++)
#pragma unroll
        for (int r=0;r<4;r++){
          const int row = i0 + wm*64 + i*16 + lq*4 + r;
          const int col = j0 + wn*64 + j*16 + lm;
          delb[(size_t)row*(4*C_) + col] = f2bf(acc[i][j][r]);
        }
  }
}

// ================= chunked scan =================
// S_t = S_{t-1}*M_t + v_t k_t^T,  M_t = diag(ew_t) + z_t b_t^T.
// Per chunk: Phi_t prefix (X from I), C_t prefix (Z from 0);
// m_t = Phi_t q_t, d_t = C_t q_t  =>  o_t = S_start m_t + d_t.

// ---- pass 1 (R1 compute structure) + fused elementwise, SOFTWARE-PIPELINED:
// R10 put the fuse math (3 expf + 18 shuffles + ~70 VALU) between the two
// staging barriers — on the serial critical path every wave must cross
// (+30us). Now the fuse math runs at the END of the compute phase on the
// prefetched raw registers (loads drain under the 8-step compute), and the
// inter-barrier window shrinks to 6 ds_writes + vb/ratio stores. Per-element
// op order and rounding identical to R10 -> bitwise-same output.
__global__ __launch_bounds__(512, 4) void chunk_mdp_kernel(
    const float* __restrict__ qm, const float* __restrict__ km,
    const float* __restrict__ vm, const float* __restrict__ vfm,
    const float* __restrict__ x, const ushort_t* __restrict__ delb,
    const float* __restrict__ w0, const float* __restrict__ v0,
    const float* __restrict__ a0,
    float* __restrict__ phi, float* __restrict__ cc, float* __restrict__ md,
    ushort_t* __restrict__ vb, float* __restrict__ ratio)
{
  const int tid  = threadIdx.x;
  const int role = tid >> 8;           // 0: phi rows, 1: cc rows (wave-uniform)
  const int row  = (tid >> 2) & 63;
  const int qr   = tid & 3;

  __shared__ float ewS[8][N_], zS[8][N_], bS[8][N_], kS[8][N_], qS[8][N_], vS[8][N_];

  const int g  = blockIdx.x;
  const int cx = g & (NC_-1), bh = g >> 4;
  const int b = bh >> 4, h = bh & 15;
  const int t0 = b*T_ + cx*L_;         // global token base

  // staging slot: step ls (0..7) within the 8-token group, dim ld
  const int ls = tid >> 6;
  const int ld = tid & 63;
  const int cdim = h*64 + ld;
  const float w0c = w0[cdim], v0c = v0[cdim], a0c = a0[cdim];

  float pq, pk, pv, pvf, px;           // raw prefetch regs
  ushort_t dwd, dvd, dad;
  float Few, Fz, Fb, Fk, Fq, Fv, Fratio;  // fuse results (pipelined)
  ushort_t Fvr;

#define LOAD_RAW(T_IDX) { \
    size_t ic = (size_t)(t0 + (T_IDX))*C_ + cdim; \
    pq = qm[ic]; pk = km[ic]; pv = vm[ic]; pvf = vfm[ic]; px = x[ic]; \
    size_t d0 = (size_t)(t0 + (T_IDX))*4*C_ + cdim; \
    dwd = delb[d0]; dvd = delb[d0+C_]; dad = delb[d0+2*C_]; }

#define FUSE_RAW() { \
    float wd = bf2f(dwd), vd = bf2f(dvd), ad = bf2f(dad); \
    float z1 = -(w0c + wd); \
    float sp = fmaxf(z1, 0.f) + log1pf(expf(-fabsf(z1))); \
    float logw = -expf(-sp - 0.5f); \
    float sv = 1.f/(1.f+expf(-(v0c + vd))); \
    float vvm = pv + (pvf - pv)*sv; \
    float av = 1.f/(1.f+expf(-(a0c + ad))); \
    Fvr = f2bf(vvm); \
    float vrf = bf2f(Fvr); \
    float ksq = pk*pk, xsq = px*px, vsq = vrf*vrf; \
    _Pragma("unroll") \
    for (int off=32; off>0; off>>=1){ \
      ksq += __shfl_xor(ksq, off, 64); \
      xsq += __shfl_xor(xsq, off, 64); \
      vsq += __shfl_xor(vsq, off, 64); \
    } \
    float kn = sqrtf(ksq); \
    float kkn = pk / fmaxf(kn, 1e-12f); \
    Few = __expf(bf2f(f2bf(logw))); \
    Fz = bf2f(f2bf(-kkn)); \
    Fb = bf2f(f2bf(kkn*av)); \
    Fk = bf2f(f2bf(pk*av)); \
    Fq = bf2f(f2bf(pq)); \
    Fv = vrf; \
    Fratio = 1.f - sqrtf(xsq)/(sqrtf(vsq)+1e-12f); }

  LOAD_RAW(ls);
  FUSE_RAW();

  float R[16];
  if (role == 0){
#pragma unroll
    for (int i=0;i<16;i++) R[i] = (qr*16+i == row) ? 1.f : 0.f;
  } else {
#pragma unroll
    for (int i=0;i<16;i++) R[i] = 0.f;
  }

  for (int tg = 0; tg < L_; tg += 8){
    __syncthreads();                   // prev group's readers done
    ewS[ls][ld] = Few;
    zS[ls][ld]  = Fz;
    bS[ls][ld]  = Fb;
    kS[ls][ld]  = Fk;
    qS[ls][ld]  = Fq;
    vS[ls][ld]  = Fv;
    {
      const int tok = t0 + tg + ls;
      vb[(size_t)tok*C_ + cdim] = Fvr;
      if (ld == 0)
        ratio[(size_t)tok*H_ + h] = Fratio;
    }
    if (tg + 8 < L_) LOAD_RAW(tg+8+ls);
    __syncthreads();                   // group visible
#pragma unroll 1
    for (int ss=0; ss<8; ss++){
      const float* zr = &zS[ss][qr*16];
      float s_ = 0.f;
#pragma unroll
      for (int i4=0;i4<4;i4++){
        float4 z4 = *(const float4*)&zr[i4*4];
        s_ = fmaf(R[i4*4+0], z4.x, s_);
        s_ = fmaf(R[i4*4+1], z4.y, s_);
        s_ = fmaf(R[i4*4+2], z4.z, s_);
        s_ = fmaf(R[i4*4+3], z4.w, s_);
      }
      s_ = quad_sum(s_);
      const float* er = &ewS[ss][qr*16];
      const float* br = &bS[ss][qr*16];
      const float* qrp = &qS[ss][qr*16];
      float o = 0.f;
      if (role == 0){
#pragma unroll
        for (int i4=0;i4<4;i4++){
          float4 e4 = *(const float4*)&er[i4*4];
          float4 b4 = *(const float4*)&br[i4*4];
          float4 q4 = *(const float4*)&qrp[i4*4];
          float t;
          t = fmaf(R[i4*4+0], e4.x, s_*b4.x); R[i4*4+0]=t; o = fmaf(t, q4.x, o);
          t = fmaf(R[i4*4+1], e4.y, s_*b4.y); R[i4*4+1]=t; o = fmaf(t, q4.y, o);
          t = fmaf(R[i4*4+2], e4.z, s_*b4.z); R[i4*4+2]=t; o = fmaf(t, q4.z, o);
          t = fmaf(R[i4*4+3], e4.w, s_*b4.w); R[i4*4+3]=t; o = fmaf(t, q4.w, o);
        }
      } else {
        const float* kr = &kS[ss][qr*16];
        const float vr = vS[ss][row];
#pragma unroll
        for (int i4=0;i4<4;i4++){
          float4 e4 = *(const float4*)&er[i4*4];
          float4 b4 = *(const float4*)&br[i4*4];
          float4 q4 = *(const float4*)&qrp[i4*4];
          float4 k4 = *(const float4*)&kr[i4*4];
          float t;
          t = fmaf(R[i4*4+0], e4.x, fmaf(s_, b4.x, vr*k4.x)); R[i4*4+0]=t; o = fmaf(t, q4.x, o);
          t = fmaf(R[i4*4+1], e4.y, fmaf(s_, b4.y, vr*k4.y)); R[i4*4+1]=t; o = fmaf(t, q4.y, o);
          t = fmaf(R[i4*4+2], e4.z, fmaf(s_, b4.z, vr*k4.z)); R[i4*4+2]=t; o = fmaf(t, q4.z, o);
          t = fmaf(R[i4*4+3], e4.w, fmaf(s_, b4.w, vr*k4.w)); R[i4*4+3]=t; o = fmaf(t, q4.w, o);
        }
      }
      o = quad_sum(o);
      if (qr == 0)
        md[((size_t)g*L_ + tg+ss)*128 + role*64 + row] = o;
    }
    if (tg + 8 < L_) FUSE_RAW();       // loads drained under compute
  }
  float* dst = (role == 0) ? phi : cc;
  const size_t base = (size_t)g*4096 + (size_t)row*64 + qr*16;
#pragma unroll
  for (int i4=0;i4<4;i4++)
    *(float4*)&dst[base + i4*4] = (float4){R[i4*4+0],R[i4*4+1],R[i4*4+2],R[i4*4+3]};
#undef LOAD_RAW
#undef FUSE_RAW
}

// ---- pass 2: sequential chunk combine per (b,h), 4 row-quarter blocks
__global__ __launch_bounds__(256) void chunk_state_kernel(
    const float* __restrict__ phi, const float* __restrict__ cc,
    float* __restrict__ sstart)
{
  const int mq = blockIdx.x;          // row quarter 0..3
  const int bh = blockIdx.y;
  const int tid = threadIdx.x;
  const int rb = tid >> 4;            // row within quarter 0..15
  const int cq = tid & 15;
  const int row = mq*16 + rb;
  __shared__ float Sld[16][65];
  __shared__ float Fld[64][68];
  float acc[4] = {0.f, 0.f, 0.f, 0.f};
  *(float4*)&Sld[rb][cq*4] = (float4){0.f,0.f,0.f,0.f};
  const float* pc = phi + (size_t)bh*NC_*4096;
  const float* cb = cc  + (size_t)bh*NC_*4096;
  float4 pf[4], pcc;
#pragma unroll
  for (int p=0;p<4;p++) pf[p] = *(const float4*)&pc[(size_t)p*1024 + tid*4];
  pcc = *(const float4*)&cb[(size_t)row*64 + cq*4];

  for (int c=0;c<NC_;c++){
    __syncthreads();
#pragma unroll
    for (int p=0;p<4;p++){
      int f = p*1024 + tid*4;
      *(float4*)&Fld[f>>6][f&63] = pf[p];
    }
    float na[4] = {pcc.x, pcc.y, pcc.z, pcc.w};
    *(float4*)&sstart[(size_t)(bh*NC_+c)*4096 + (size_t)row*64 + cq*4] =
        (float4){acc[0],acc[1],acc[2],acc[3]};
    if (c+1 < NC_){
#pragma unroll
      for (int p=0;p<4;p++) pf[p] = *(const float4*)&pc[(size_t)(c+1)*4096 + p*1024 + tid*4];
      pcc = *(const float4*)&cb[(size_t)(c+1)*4096 + (size_t)row*64 + cq*4];
    }
    __syncthreads();
#pragma unroll 1
    for (int k0=0;k0<64;k0+=4){
      const float4 sr = *(const float4*)&Sld[rb][k0];
      const float4 f0 = *(const float4*)&Fld[k0+0][cq*4];
      const float4 f1 = *(const float4*)&Fld[k0+1][cq*4];
      const float4 f2 = *(const float4*)&Fld[k0+2][cq*4];
      const float4 f3 = *(const float4*)&Fld[k0+3][cq*4];
      na[0] = fmaf(sr.x, f0.x, na[0]); na[0] = fmaf(sr.y, f1.x, na[0]);
      na[0] = fmaf(sr.z, f2.x, na[0]); na[0] = fmaf(sr.w, f3.x, na[0]);
      na[1] = fmaf(sr.x, f0.y, na[1]); na[1] = fmaf(sr.y, f1.y, na[1]);
      na[1] = fmaf(sr.z, f2.y, na[1]); na[1] = fmaf(sr.w, f3.y, na[1]);
      na[2] = fmaf(sr.x, f0.z, na[2]); na[2] = fmaf(sr.y, f1.z, na[2]);
      na[2] = fmaf(sr.z, f2.z, na[2]); na[2] = fmaf(sr.w, f3.z, na[2]);
      na[3] = fmaf(sr.x, f0.w, na[3]); na[3] = fmaf(sr.y, f1.w, na[3]);
      na[3] = fmaf(sr.z, f2.w, na[3]); na[3] = fmaf(sr.w, f3.w, na[3]);
    }
    __syncthreads();
    *(float4*)&Sld[rb][cq*4] = (float4){na[0],na[1],na[2],na[3]};
#pragma unroll
    for (int i=0;i<4;i++) acc[i] = na[i];
  }
}

// ---- pass 3: o = S_start·m + d, epilogue, emit bf16 y
__global__ __launch_bounds__(256) void chunk_emit_kernel(
    const ushort_t* __restrict__ vb, const ushort_t* __restrict__ delb,
    const float* __restrict__ ratio, const float* __restrict__ rk,
    const float* __restrict__ sstart, const float* __restrict__ md,
    ushort_t* __restrict__ y)
{
  const int blk = blockIdx.x;
  const int c  = blk & (NC_-1);
  const int bh = blk >> 4;
  const int b = bh >> 4, h = bh & 15;
  const int tid = threadIdx.x;
  const int v = tid & 63;
  const int tg = tid >> 6;

  float4 sr[16];
  const float4* sp = (const float4*)(sstart + (size_t)blk*4096 + (size_t)v*64);
#pragma unroll
  for (int f=0;f<16;f++) sr[f] = sp[f];
  const float sigrk = 1.f/(1.f+__expf(-rk[h*64+v]));

#pragma unroll 1
  for (int ss=0; ss<32; ss++){
    const int t = tg*32 + ss;
    const int token = b*T_ + c*L_ + t;
    const float* mrow = md + ((size_t)blk*L_ + t)*128;
    float o0=0.f,o1=0.f,o2=0.f,o3=0.f;
#pragma unroll
    for (int f=0;f<16;f+=4){
      float4 m0 = ((const float4*)mrow)[f+0];
      float4 m1 = ((const float4*)mrow)[f+1];
      float4 m2 = ((const float4*)mrow)[f+2];
      float4 m3 = ((const float4*)mrow)[f+3];
      o0 = fmaf(sr[f+0].x,m0.x, fmaf(sr[f+0].y,m0.y, fmaf(sr[f+0].z,m0.z, fmaf(sr[f+0].w,m0.w, o0))));
      o1 = fmaf(sr[f+1].x,m1.x, fmaf(sr[f+1].y,m1.y, fmaf(sr[f+1].z,m1.z, fmaf(sr[f+1].w,m1.w, o1))));
      o2 = fmaf(sr[f+2].x,m2.x, fmaf(sr[f+2].y,m2.y, fmaf(sr[f+2].z,m2.z, fmaf(sr[f+2].w,m2.w, o2))));
      o3 = fmaf(sr[f+3].x,m3.x, fmaf(sr[f+3].y,m3.y, fmaf(sr[f+3].z,m3.z, fmaf(sr[f+3].w,m3.w, o3))));
    }
    float o = ((o0+o1)+(o2+o3)) + mrow[64 + v];
    const float vt = bf2f(vb[(size_t)token*C_ + h*64 + v]);
    const float uv = ratio[(size_t)token*H_ + h];
    const float gv = 1.f + bf2f(delb[(size_t)token*4*C_ + 3*C_ + h*64 + v]);
    y[(size_t)token*C_ + h*64 + v] = f2bf((o*0.125f + vt*uv*sigrk)*gv);
  }
}

extern "C" void kernel_launch(void* const* d_in, const int* in_sizes, int n_in,
                              void* d_out, int out_size, void* d_ws, size_t ws_size,
                              hipStream_t stream)
{
  const float* residual = (const float*)d_in[0];
  const float* x    = (const float*)d_in[1];
  const float* x0   = (const float*)d_in[2];
  const float* dx0  = (const float*)d_in[3];
  const float* Wq   = (const float*)d_in[4];
  const float* Wk   = (const float*)d_in[5];
  const float* Wv   = (const float*)d_in[6];
  const float* Wpr  = (const float*)d_in[7];
  const float* x_q  = (const float*)d_in[8];
  const float* x_k  = (const float*)d_in[9];
  const float* x_v  = (const float*)d_in[10];
  const float* v0   = (const float*)d_in[11];
  const float* w0   = (const float*)d_in[12];
  const float* a0   = (const float*)d_in[13];
  const float* miss = (const float*)d_in[14];
  const float* rk   = (const float*)d_in[15];
  float* out = (float*)d_out;

  char* ws = (char*)d_ws;
  const size_t MB = (size_t)1 << 20;
  // phase A (pre-scan):
  float*    q_m    = (float*)(ws + 0*MB);      // [0,64): q,k,v,vf f32 (live thru mdp)
  float*    k_m    = (float*)(ws + 16*MB);
  float*    v_m    = (float*)(ws + 32*MB);
  float*    vf_m   = (float*)(ws + 48*MB);
  ushort_t* delb   = (ushort_t*)(ws + 64*MB);  // [64,96) bf16 deltas (live thru emit)
  ushort_t* Ab     = (ushort_t*)(ws + 96*MB);  // [96,128): Aq,Ak,Av,Axf (dead after qkvm)
  ushort_t* Xb     = (ushort_t*)(ws + 128*MB); // [128,136) (dead after qkvm)
  ushort_t* Wb     = (ushort_t*)(ws + 136*MB); // [136,144) (dead after qkvm)
  ushort_t* Wpb    = (ushort_t*)(ws + 160*MB); // [160,162) (live to end)
  ushort_t* missT  = (ushort_t*)(ws + 162*MB); // [162,163) (dead after qkvm)
  float*    ratio  = (float*)(ws + 163*MB);    // 256KB
  // phase C (scan onward — overlays only qkvm-dead regions):
  float*    mdbuf  = (float*)(ws + 96*MB);     // [96,128) over Ab (32MB)
  float*    phi    = (float*)(ws + 128*MB);    // [128,136) over Xb
  float*    cc     = (float*)(ws + 136*MB);    // [136,144) over Wb
  float*    sstart = (float*)(ws + 144*MB);    // [144,152) (old g_m space)
  ushort_t* vb     = (ushort_t*)(ws + 152*MB); // [152,160) bf16 v for emit
  ushort_t* yb     = (ushort_t*)(ws + 48*MB);  // over vf_m (emit runs after mdp)

  ushort_t* Aq  = Ab + 0*(size_t)M_*C_;
  ushort_t* Ak  = Ab + 1*(size_t)M_*C_;
  ushort_t* Av  = Ab + 2*(size_t)M_*C_;
  ushort_t* Axf = Ab + 3*(size_t)M_*C_;

  dim3 blk(256);
  prep_all<<<4096 + 5*1024 + 64, blk, 0, stream>>>(
      x, x0, dx0, x_q, x_k, x_v, Wq, Wk, Wv, Wpr, miss,
      Aq, Ak, Av, Axf, Xb, Wb, Wpb, missT);
  qkvm_gemm<<<2048, blk, 0, stream>>>(Ab, Wb, Xb, missT, q_m, delb);
  chunk_mdp_kernel<<<B_*H_*NC_, dim3(512), 0, stream>>>(
      q_m, k_m, v_m, vf_m, x, delb, w0, v0, a0, phi, cc, mdbuf, vb, ratio);
  chunk_state_kernel<<<dim3(4, B_*H_), blk, 0, stream>>>(phi, cc, sstart);
  chunk_emit_kernel<<<B_*H_*NC_, blk, 0, stream>>>(vb, delb, ratio, rk, sstart, mdbuf, yb);
  mfma_gemm<<<dim3(C_/128, M_/128, 1), blk, 0, stream>>>(
      yb, C_, 0, Wpb, C_, 0, out, C_, 0, 0, residual, C_);
}

// Round 12
// 461.387 us; speedup vs baseline: 1.0375x; 1.0375x over previous
//
#include <hip/hip_runtime.h>
#include <stdint.h>
#include <stddef.h>

#define B_ 2
#define T_ 2048
#define C_ 1024
#define H_ 16
#define N_ 64
#define M_ (B_*T_)
#define L_ 128              // chunk length
#define NC_ (T_/L_)         // 16 chunks

typedef unsigned short ushort_t;
typedef __attribute__((ext_vector_type(8))) __bf16 bf16x8;
typedef __attribute__((ext_vector_type(4))) float  f32x4;

__device__ __forceinline__ ushort_t f2bf(float x){
  uint32_t u = __float_as_uint(x);
  u += 0x7fffu + ((u >> 16) & 1u);   // RNE to bf16 (inputs finite)
  return (ushort_t)(u >> 16);
}
__device__ __forceinline__ float bf2f(uint32_t hu){
  return __uint_as_float(hu << 16);
}
// sum across 4-lane quad via DPP (VALU pipe, not ds_swizzle)
__device__ __forceinline__ float quad_sum(float v){
  float a = __int_as_float(__builtin_amdgcn_mov_dpp(__float_as_int(v), 0xB1, 0xF, 0xF, true)); // xor 1
  v += a;
  float b = __int_as_float(__builtin_amdgcn_mov_dpp(__float_as_int(v), 0x4E, 0xF, 0xF, true)); // xor 2
  return v + b;
}

// ---------------- merged prep: activations + weights + missT ----------------
__device__ __forceinline__ ushort4 mixq4(float4 a, float4 p, float4 c){
  ushort4 o;
  o.x = f2bf(fmaf(p.x - a.x, c.x, a.x));
  o.y = f2bf(fmaf(p.y - a.y, c.y, a.y));
  o.z = f2bf(fmaf(p.z - a.z, c.z, a.z));
  o.w = f2bf(fmaf(p.w - a.w, c.w, a.w));
  return o;
}
__global__ __launch_bounds__(256) void prep_all(
    const float* __restrict__ x, const float* __restrict__ x0,
    const float* __restrict__ dx0,
    const float* __restrict__ xq, const float* __restrict__ xk,
    const float* __restrict__ xv,
    const float* __restrict__ Wq, const float* __restrict__ Wk,
    const float* __restrict__ Wv, const float* __restrict__ Wp,
    const float* __restrict__ miss,
    ushort_t* __restrict__ Aq, ushort_t* __restrict__ Ak,
    ushort_t* __restrict__ Av, ushort_t* __restrict__ Axf,
    ushort_t* __restrict__ Xb,
    ushort_t* __restrict__ Wb, ushort_t* __restrict__ Wpb,
    ushort_t* __restrict__ missT)
{
  __shared__ ushort_t tile[128][66];
  const int blk = blockIdx.x;
  const int tid = threadIdx.x;
  if (blk < 4096){
    const int idx = blk*256 + tid;
    const int col4 = idx & 255;
    const int i = idx >> 8;
    const int t = i & (T_-1);
    float4 a = ((const float4*)x)[idx];
    float4 p = {0.f,0.f,0.f,0.f};
    if (t > 0) p = ((const float4*)x)[idx - 256];
    float4 cq = ((const float4*)xq)[col4];
    float4 ck = ((const float4*)xk)[col4];
    float4 cv = ((const float4*)xv)[col4];
    ((ushort4*)Aq)[idx] = mixq4(a, p, cq);
    ((ushort4*)Ak)[idx] = mixq4(a, p, ck);
    ((ushort4*)Av)[idx] = mixq4(a, p, cv);
    float4 z = ((const float4*)x0)[idx];
    float4 d = ((const float4*)dx0)[idx];
    ushort4 of;
    of.x = f2bf(fmaf(d.x, cv.x, z.x));
    of.y = f2bf(fmaf(d.y, cv.y, z.y));
    of.z = f2bf(fmaf(d.z, cv.z, z.z));
    of.w = f2bf(fmaf(d.w, cv.w, z.w));
    ((ushort4*)Axf)[idx] = of;
    ushort4 ob = {f2bf(a.x), f2bf(a.y), f2bf(a.z), f2bf(a.w)};
    ((ushort4*)Xb)[idx] = ob;
  } else if (blk < 4096 + 5*1024){
    const int y = (blk - 4096) >> 10;
    const float* src = (y==0)?Wq:(y==1)?Wk:(y<4)?Wv:Wp;
    ushort_t* dst = (y<4) ? Wb + (size_t)y*C_*C_ : Wpb;
    const int idx = ((blk - 4096) & 1023)*256 + tid;
    float4 v = ((const float4*)src)[idx];
    ushort4 o = {f2bf(v.x), f2bf(v.y), f2bf(v.z), f2bf(v.w)};
    ((ushort4*)dst)[idx] = o;
  } else {
    const int j0 = (blk - 4096 - 5*1024)*64;
#pragma unroll
    for (int rep=0; rep<8; rep++){
      int k = rep*16 + (tid>>4);
      int jj = (tid&15)*4;
      float4 v = *(const float4*)&miss[(size_t)k*4096 + j0 + jj];
      tile[k][jj+0]=f2bf(v.x); tile[k][jj+1]=f2bf(v.y);
      tile[k][jj+2]=f2bf(v.z); tile[k][jj+3]=f2bf(v.w);
    }
    __syncthreads();
#pragma unroll
    for (int rep=0; rep<8; rep++){
      int j = tid>>2;
      int kk = (tid&3)*32 + rep*4;
      ushort4 o = {tile[kk+0][j], tile[kk+1][j], tile[kk+2][j], tile[kk+3][j]};
      *(ushort4*)&missT[(size_t)(j0+j)*128 + kk] = o;
    }
  }
}

// ---------------- bf16 MFMA GEMM (m97 structure), generic (out-proj) -------
__global__ __launch_bounds__(256, 2) void mfma_gemm(
    const ushort_t* __restrict__ Ab, int lda, int64_t Asz,
    const ushort_t* __restrict__ Bbp, int ldb, int64_t Bsz,
    void* __restrict__ Cb, int ldc, int64_t Csz, int c_bf16,
    const float* __restrict__ resid, int K)
{
  const ushort_t* A  = Ab  + (size_t)blockIdx.z * Asz;
  const ushort_t* Bm = Bbp + (size_t)blockIdx.z * Bsz;
  const int i0 = blockIdx.y * 128;
  const int j0 = blockIdx.x * 128;
  const int tid = threadIdx.x;
  const int lane = tid & 63;
  const int w = tid >> 6;
  const int wm = w & 1, wn = w >> 1;

  __shared__ ushort_t As[128*32];
  __shared__ ushort_t Bs[128*32];

  f32x4 acc[4][4];
#pragma unroll
  for (int i=0;i<4;i++)
#pragma unroll
    for (int j=0;j<4;j++) acc[i][j] = (f32x4){0.f,0.f,0.f,0.f};

  const int lr = lane >> 2;
  const int ls = lane & 3;
  const ushort_t* ga = A  + (size_t)(i0 + w*32 + lr)*lda + ls*8;
  const ushort_t* gb = Bm + (size_t)(j0 + w*32 + lr)*ldb + ls*8;
  const int lm = lane & 15, lq = lane >> 4;

  for (int k0 = 0; k0 < K; k0 += 32){
    __syncthreads();
#pragma unroll
    for (int p=0;p<2;p++){
      __builtin_amdgcn_global_load_lds(
        (const __attribute__((address_space(1))) void*)(ga + (size_t)p*16*lda + k0),
        (__attribute__((address_space(3))) void*)&As[(w*32 + p*16)*32], 16, 0, 0);
      __builtin_amdgcn_global_load_lds(
        (const __attribute__((address_space(1))) void*)(gb + (size_t)p*16*ldb + k0),
        (__attribute__((address_space(3))) void*)&Bs[(w*32 + p*16)*32], 16, 0, 0);
    }
    __syncthreads();
    bf16x8 af[4], bfr[4];
#pragma unroll
    for (int i=0;i<4;i++)
      af[i] = *(const bf16x8*)&As[(wm*64 + i*16 + lm)*32 + lq*8];
#pragma unroll
    for (int j=0;j<4;j++)
      bfr[j] = *(const bf16x8*)&Bs[(wn*64 + j*16 + lm)*32 + lq*8];
#pragma unroll
    for (int i=0;i<4;i++)
#pragma unroll
      for (int j=0;j<4;j++)
        acc[i][j] = __builtin_amdgcn_mfma_f32_16x16x32_bf16(af[i], bfr[j], acc[i][j], 0, 0, 0);
  }

  if (!c_bf16){
    float* C = (float*)Cb + (size_t)blockIdx.z * Csz;
#pragma unroll
    for (int i=0;i<4;i++)
#pragma unroll
      for (int j=0;j<4;j++)
#pragma unroll
        for (int r=0;r<4;r++){
          const int row = i0 + wm*64 + i*16 + lq*4 + r;
          const int col = j0 + wn*64 + j*16 + lm;
          float v = acc[i][j][r];
          if (resid) v += resid[(size_t)row*ldc + col];
          C[(size_t)row*ldc + col] = v;
        }
  } else {
    ushort_t* C = (ushort_t*)Cb + (size_t)blockIdx.z * Csz;
#pragma unroll
    for (int i=0;i<4;i++)
#pragma unroll
      for (int j=0;j<4;j++)
#pragma unroll
        for (int r=0;r<4;r++){
          const int row = i0 + wm*64 + i*16 + lq*4 + r;
          const int col = j0 + wn*64 + j*16 + lm;
          C[(size_t)row*ldc + col] = f2bf(acc[i][j][r]);
        }
  }
}

// ---------------- merged QKV (z=0..3) + miss GEMM, one launch -------------
__global__ __launch_bounds__(256, 2) void qkvm_gemm(
    const ushort_t* __restrict__ Ab4, const ushort_t* __restrict__ Wb,
    const ushort_t* __restrict__ Xb,  const ushort_t* __restrict__ missT,
    float* __restrict__ qkvf, ushort_t* __restrict__ delb)
{
  const int bid = blockIdx.x;
  const bool isQKV = bid < 1024;
  const ushort_t* A; const ushort_t* Bm;
  int i0, j0, ldb, K, z = 0;
  if (isQKV){
    z = bid >> 8;
    const int g = bid & 255;
    j0 = (g & 7) * 128;
    i0 = (g >> 3) * 128;
    A  = Ab4 + (size_t)z*M_*C_;
    Bm = Wb  + (size_t)z*C_*C_;
    ldb = C_; K = C_;
  } else {
    const int g = bid - 1024;
    j0 = (g & 31) * 128;
    i0 = (g >> 5) * 128;
    A = Xb; Bm = missT;
    ldb = 128; K = 128;
  }
  const int lda = C_;
  const int tid = threadIdx.x;
  const int lane = tid & 63;
  const int w = tid >> 6;
  const int wm = w & 1, wn = w >> 1;

  __shared__ ushort_t As[128*32];
  __shared__ ushort_t Bs[128*32];

  f32x4 acc[4][4];
#pragma unroll
  for (int i=0;i<4;i++)
#pragma unroll
    for (int j=0;j<4;j++) acc[i][j] = (f32x4){0.f,0.f,0.f,0.f};

  const int lr = lane >> 2;
  const int ls = lane & 3;
  const ushort_t* ga = A  + (size_t)(i0 + w*32 + lr)*lda + ls*8;
  const ushort_t* gb = Bm + (size_t)(j0 + w*32 + lr)*ldb + ls*8;
  const int lm = lane & 15, lq = lane >> 4;

  for (int k0 = 0; k0 < K; k0 += 32){
    __syncthreads();
#pragma unroll
    for (int p=0;p<2;p++){
      __builtin_amdgcn_global_load_lds(
        (const __attribute__((address_space(1))) void*)(ga + (size_t)p*16*lda + k0),
        (__attribute__((address_space(3))) void*)&As[(w*32 + p*16)*32], 16, 0, 0);
      __builtin_amdgcn_global_load_lds(
        (const __attribute__((address_space(1))) void*)(gb + (size_t)p*16*ldb + k0),
        (__attribute__((address_space(3))) void*)&Bs[(w*32 + p*16)*32], 16, 0, 0);
    }
    __syncthreads();
    bf16x8 af[4], bfr[4];
#pragma unroll
    for (int i=0;i<4;i++)
      af[i] = *(const bf16x8*)&As[(wm*64 + i*16 + lm)*32 + lq*8];
#pragma unroll
    for (int j=0;j<4;j++)
      bfr[j] = *(const bf16x8*)&Bs[(wn*64 + j*16 + lm)*32 + lq*8];
#pragma unroll
    for (int i=0;i<4;i++)
#pragma unroll
      for (int j=0;j<4;j++)
        acc[i][j] = __builtin_amdgcn_mfma_f32_16x16x32_bf16(af[i], bfr[j], acc[i][j], 0, 0, 0);
  }

  if (isQKV){
    float* C = qkvf + (size_t)z*M_*C_;
#pragma unroll
    for (int i=0;i<4;i++)
#pragma unroll
      for (int j=0;j<4;j++)
#pragma unroll
        for (int r=0;r<4;r++){
          const int row = i0 + wm*64 + i*16 + lq*4 + r;
          const int col = j0 + wn*64 + j*16 + lm;
          C[(size_t)row*C_ + col] = acc[i][j][r];
        }
  } else {
#pragma unroll
    for (int i=0;i<4;i++)
#pragma unroll
      for (int j=0;j<4;j++)
#pragma unroll
        for (int r=0;r<4;r++){
          const int row = i0 + wm*64 + i*16 + lq*4 + r;
          const int col = j0 + wn*64 + j*16 + lm;
          delb[(size_t)row*(4*C_) + col] = f2bf(acc[i][j][r]);
        }
  }
}

// ================= chunked scan =================
// S_t = S_{t-1}*M_t + v_t k_t^T,  M_t = diag(ew_t) + z_t b_t^T.
// Per chunk: Phi_t prefix (X from I), C_t prefix (Z from 0);
// m_t = Phi_t q_t, d_t = C_t q_t  =>  o_t = S_start m_t + d_t.

// ---- pass 1: PRODUCER/CONSUMER wave specialization (R11 PM: any work in a
// barrier-lockstep loop is on the critical path; only non-lockstep waves can
// hide it). 768 threads: waves 0-7 = consumers (exact R1 compute layout),
// waves 8-11 = producers owning all fuse+staging. Double-buffered LDS with
// COMPILE-TIME buffer indices (pair loop unrolled — R2 lesson). 1 barrier
// per group (was 2). Barriers matched 17/17 across both role branches
// (separate loops -> regalloc overlaps R[] with producer F/raw, VGPR<=64
// for 2 blocks/CU = 24 waves). Per-element math/rounding identical.
__global__ __launch_bounds__(768, 8) void chunk_mdp_kernel(
    const float* __restrict__ qm, const float* __restrict__ km,
    const float* __restrict__ vm, const float* __restrict__ vfm,
    const float* __restrict__ x, const ushort_t* __restrict__ delb,
    const float* __restrict__ w0, const float* __restrict__ v0,
    const float* __restrict__ a0,
    float* __restrict__ phi, float* __restrict__ cc, float* __restrict__ md,
    ushort_t* __restrict__ vb, float* __restrict__ ratio)
{
  const int tid = threadIdx.x;
  __shared__ float ewS[2][8][N_], zS[2][8][N_], bS[2][8][N_],
                   kS[2][8][N_], qS[2][8][N_], vS[2][8][N_];

  const int g  = blockIdx.x;
  const int cx = g & (NC_-1), bh = g >> 4;
  const int b = bh >> 4, h = bh & 15;
  const int t0 = b*T_ + cx*L_;
  const int NG = L_/8;                 // 16 groups, 8 pairs

  if (tid < 512){
    // ================= consumers: waves 0-7 =================
    const int role = tid >> 8;
    const int row  = (tid >> 2) & 63;
    const int qr   = tid & 3;
    float R[16];
    if (role == 0){
#pragma unroll
      for (int i=0;i<16;i++) R[i] = (qr*16+i == row) ? 1.f : 0.f;
    } else {
#pragma unroll
      for (int i=0;i<16;i++) R[i] = 0.f;
    }

#define COMPUTE(BUF, GRP) { \
    _Pragma("unroll 1") \
    for (int ss=0; ss<8; ss++){ \
      const float* zr = &zS[BUF][ss][qr*16]; \
      float s_ = 0.f; \
      _Pragma("unroll") \
      for (int i4=0;i4<4;i4++){ \
        float4 z4 = *(const float4*)&zr[i4*4]; \
        s_ = fmaf(R[i4*4+0], z4.x, s_); \
        s_ = fmaf(R[i4*4+1], z4.y, s_); \
        s_ = fmaf(R[i4*4+2], z4.z, s_); \
        s_ = fmaf(R[i4*4+3], z4.w, s_); \
      } \
      s_ = quad_sum(s_); \
      const float* er = &ewS[BUF][ss][qr*16]; \
      const float* br = &bS[BUF][ss][qr*16]; \
      const float* qrp = &qS[BUF][ss][qr*16]; \
      float o = 0.f; \
      if (role == 0){ \
        _Pragma("unroll") \
        for (int i4=0;i4<4;i4++){ \
          float4 e4 = *(const float4*)&er[i4*4]; \
          float4 b4 = *(const float4*)&br[i4*4]; \
          float4 q4 = *(const float4*)&qrp[i4*4]; \
          float t; \
          t = fmaf(R[i4*4+0], e4.x, s_*b4.x); R[i4*4+0]=t; o = fmaf(t, q4.x, o); \
          t = fmaf(R[i4*4+1], e4.y, s_*b4.y); R[i4*4+1]=t; o = fmaf(t, q4.y, o); \
          t = fmaf(R[i4*4+2], e4.z, s_*b4.z); R[i4*4+2]=t; o = fmaf(t, q4.z, o); \
          t = fmaf(R[i4*4+3], e4.w, s_*b4.w); R[i4*4+3]=t; o = fmaf(t, q4.w, o); \
        } \
      } else { \
        const float* kr = &kS[BUF][ss][qr*16]; \
        const float vr = vS[BUF][ss][row]; \
        _Pragma("unroll") \
        for (int i4=0;i4<4;i4++){ \
          float4 e4 = *(const float4*)&er[i4*4]; \
          float4 b4 = *(const float4*)&br[i4*4]; \
          float4 q4 = *(const float4*)&qrp[i4*4]; \
          float4 k4 = *(const float4*)&kr[i4*4]; \
          float t; \
          t = fmaf(R[i4*4+0], e4.x, fmaf(s_, b4.x, vr*k4.x)); R[i4*4+0]=t; o = fmaf(t, q4.x, o); \
          t = fmaf(R[i4*4+1], e4.y, fmaf(s_, b4.y, vr*k4.y)); R[i4*4+1]=t; o = fmaf(t, q4.y, o); \
          t = fmaf(R[i4*4+2], e4.z, fmaf(s_, b4.z, vr*k4.z)); R[i4*4+2]=t; o = fmaf(t, q4.z, o); \
          t = fmaf(R[i4*4+3], e4.w, fmaf(s_, b4.w, vr*k4.w)); R[i4*4+3]=t; o = fmaf(t, q4.w, o); \
        } \
      } \
      o = quad_sum(o); \
      if (qr == 0) \
        md[((size_t)g*L_ + (GRP)*8+ss)*128 + role*64 + row] = o; \
    } }

    __syncthreads();                   // buf0 (group 0) published
#pragma unroll 1
    for (int pair = 0; pair < NG/2; ++pair){
      COMPUTE(0, pair*2);
      __syncthreads();
      COMPUTE(1, pair*2+1);
      __syncthreads();
    }
#undef COMPUTE
    float* dst = (role == 0) ? phi : cc;
    const size_t base = (size_t)g*4096 + (size_t)row*64 + qr*16;
#pragma unroll
    for (int i4=0;i4<4;i4++)
      *(float4*)&dst[base + i4*4] = (float4){R[i4*4+0],R[i4*4+1],R[i4*4+2],R[i4*4+3]};
  } else {
    // ================= producers: waves 8-11 =================
    const int ptid = tid - 512;
    const int pw = ptid >> 6;          // wave handles steps pw and pw+4
    const int pl = ptid & 63;          // dim within head
    const int cdim = h*64 + pl;
    const float w0c = w0[cdim], v0c = v0[cdim], a0c = a0[cdim];

    float pq[2], pk[2], pv[2], pvf[2], px[2];
    ushort_t dwd[2], dvd[2], dad[2];
    float Few[2], Fz[2], Fb[2], Fk[2], Fq[2], Fv[2], Fratio[2];
    ushort_t Fvr[2];

#define LOAD_RAW(GRP) { \
    _Pragma("unroll") \
    for (int i=0;i<2;i++){ \
      int tok = t0 + (GRP)*8 + pw + i*4; \
      size_t ic = (size_t)tok*C_ + cdim; \
      pq[i] = qm[ic]; pk[i] = km[ic]; pv[i] = vm[ic]; pvf[i] = vfm[ic]; px[i] = x[ic]; \
      size_t d0 = (size_t)tok*4*C_ + cdim; \
      dwd[i] = delb[d0]; dvd[i] = delb[d0+C_]; dad[i] = delb[d0+2*C_]; \
    } }

#define FUSE_ALL() { \
    _Pragma("unroll") \
    for (int i=0;i<2;i++){ \
      float wd = bf2f(dwd[i]), vd = bf2f(dvd[i]), ad = bf2f(dad[i]); \
      float z1 = -(w0c + wd); \
      float sp = fmaxf(z1, 0.f) + log1pf(expf(-fabsf(z1))); \
      float logw = -expf(-sp - 0.5f); \
      float sv = 1.f/(1.f+expf(-(v0c + vd))); \
      float vvm = pv[i] + (pvf[i] - pv[i])*sv; \
      float av = 1.f/(1.f+expf(-(a0c + ad))); \
      Fvr[i] = f2bf(vvm); \
      float vrf = bf2f(Fvr[i]); \
      float ksq = pk[i]*pk[i], xsq = px[i]*px[i], vsq = vrf*vrf; \
      _Pragma("unroll") \
      for (int off=32; off>0; off>>=1){ \
        ksq += __shfl_xor(ksq, off, 64); \
        xsq += __shfl_xor(xsq, off, 64); \
        vsq += __shfl_xor(vsq, off, 64); \
      } \
      float kn = sqrtf(ksq); \
      float kkn = pk[i] / fmaxf(kn, 1e-12f); \
      Few[i] = __expf(bf2f(f2bf(logw))); \
      Fz[i]  = bf2f(f2bf(-kkn)); \
      Fb[i]  = bf2f(f2bf(kkn*av)); \
      Fk[i]  = bf2f(f2bf(pk[i]*av)); \
      Fq[i]  = bf2f(f2bf(pq[i])); \
      Fv[i]  = vrf; \
      Fratio[i] = 1.f - sqrtf(xsq)/(sqrtf(vsq)+1e-12f); \
    } }

#define WRITE_F(BUF, GRP) { \
    _Pragma("unroll") \
    for (int i=0;i<2;i++){ \
      int st = pw + i*4; \
      ewS[BUF][st][pl] = Few[i]; \
      zS[BUF][st][pl]  = Fz[i]; \
      bS[BUF][st][pl]  = Fb[i]; \
      kS[BUF][st][pl]  = Fk[i]; \
      qS[BUF][st][pl]  = Fq[i]; \
      vS[BUF][st][pl]  = Fv[i]; \
      int tok = t0 + (GRP)*8 + st; \
      vb[(size_t)tok*C_ + cdim] = Fvr[i]; \
      if (pl == 0) ratio[(size_t)tok*H_ + h] = Fratio[i]; \
    } }

    LOAD_RAW(0);
    FUSE_ALL();
    WRITE_F(0, 0);
    LOAD_RAW(1);
    __syncthreads();                   // buf0 (group 0) published
#pragma unroll 1
    for (int pair = 0; pair < NG/2; ++pair){
      const int gB = pair*2 + 1;
      // consumers compute buf0(group gB-1); we fill buf1(group gB)
      FUSE_ALL();                      // raw = group gB
      WRITE_F(1, gB);
      if (gB + 1 < NG) LOAD_RAW(gB + 1);
      __syncthreads();
      // consumers compute buf1(group gB); we fill buf0(group gB+1)
      if (gB + 1 < NG){
        FUSE_ALL();                    // raw = group gB+1
        WRITE_F(0, gB + 1);
        if (gB + 2 < NG) LOAD_RAW(gB + 2);
      }
      __syncthreads();
    }
#undef LOAD_RAW
#undef FUSE_ALL
#undef WRITE_F
  }
}

// ---- pass 2: sequential chunk combine per (b,h), 4 row-quarter blocks
__global__ __launch_bounds__(256) void chunk_state_kernel(
    const float* __restrict__ phi, const float* __restrict__ cc,
    float* __restrict__ sstart)
{
  const int mq = blockIdx.x;          // row quarter 0..3
  const int bh = blockIdx.y;
  const int tid = threadIdx.x;
  const int rb = tid >> 4;            // row within quarter 0..15
  const int cq = tid & 15;
  const int row = mq*16 + rb;
  __shared__ float Sld[16][65];
  __shared__ float Fld[64][68];
  float acc[4] = {0.f, 0.f, 0.f, 0.f};
  *(float4*)&Sld[rb][cq*4] = (float4){0.f,0.f,0.f,0.f};
  const float* pc = phi + (size_t)bh*NC_*4096;
  const float* cb = cc  + (size_t)bh*NC_*4096;
  float4 pf[4], pcc;
#pragma unroll
  for (int p=0;p<4;p++) pf[p] = *(const float4*)&pc[(size_t)p*1024 + tid*4];
  pcc = *(const float4*)&cb[(size_t)row*64 + cq*4];

  for (int c=0;c<NC_;c++){
    __syncthreads();
#pragma unroll
    for (int p=0;p<4;p++){
      int f = p*1024 + tid*4;
      *(float4*)&Fld[f>>6][f&63] = pf[p];
    }
    float na[4] = {pcc.x, pcc.y, pcc.z, pcc.w};
    *(float4*)&sstart[(size_t)(bh*NC_+c)*4096 + (size_t)row*64 + cq*4] =
        (float4){acc[0],acc[1],acc[2],acc[3]};
    if (c+1 < NC_){
#pragma unroll
      for (int p=0;p<4;p++) pf[p] = *(const float4*)&pc[(size_t)(c+1)*4096 + p*1024 + tid*4];
      pcc = *(const float4*)&cb[(size_t)(c+1)*4096 + (size_t)row*64 + cq*4];
    }
    __syncthreads();
#pragma unroll 1
    for (int k0=0;k0<64;k0+=4){
      const float4 sr = *(const float4*)&Sld[rb][k0];
      const float4 f0 = *(const float4*)&Fld[k0+0][cq*4];
      const float4 f1 = *(const float4*)&Fld[k0+1][cq*4];
      const float4 f2 = *(const float4*)&Fld[k0+2][cq*4];
      const float4 f3 = *(const float4*)&Fld[k0+3][cq*4];
      na[0] = fmaf(sr.x, f0.x, na[0]); na[0] = fmaf(sr.y, f1.x, na[0]);
      na[0] = fmaf(sr.z, f2.x, na[0]); na[0] = fmaf(sr.w, f3.x, na[0]);
      na[1] = fmaf(sr.x, f0.y, na[1]); na[1] = fmaf(sr.y, f1.y, na[1]);
      na[1] = fmaf(sr.z, f2.y, na[1]); na[1] = fmaf(sr.w, f3.y, na[1]);
      na[2] = fmaf(sr.x, f0.z, na[2]); na[2] = fmaf(sr.y, f1.z, na[2]);
      na[2] = fmaf(sr.z, f2.z, na[2]); na[2] = fmaf(sr.w, f3.z, na[2]);
      na[3] = fmaf(sr.x, f0.w, na[3]); na[3] = fmaf(sr.y, f1.w, na[3]);
      na[3] = fmaf(sr.z, f2.w, na[3]); na[3] = fmaf(sr.w, f3.w, na[3]);
    }
    __syncthreads();
    *(float4*)&Sld[rb][cq*4] = (float4){na[0],na[1],na[2],na[3]};
#pragma unroll
    for (int i=0;i<4;i++) acc[i] = na[i];
  }
}

// ---- pass 3: o = S_start·m + d, epilogue, emit bf16 y
__global__ __launch_bounds__(256) void chunk_emit_kernel(
    const ushort_t* __restrict__ vb, const ushort_t* __restrict__ delb,
    const float* __restrict__ ratio, const float* __restrict__ rk,
    const float* __restrict__ sstart, const float* __restrict__ md,
    ushort_t* __restrict__ y)
{
  const int blk = blockIdx.x;
  const int c  = blk & (NC_-1);
  const int bh = blk >> 4;
  const int b = bh >> 4, h = bh & 15;
  const int tid = threadIdx.x;
  const int v = tid & 63;
  const int tg = tid >> 6;

  float4 sr[16];
  const float4* sp = (const float4*)(sstart + (size_t)blk*4096 + (size_t)v*64);
#pragma unroll
  for (int f=0;f<16;f++) sr[f] = sp[f];
  const float sigrk = 1.f/(1.f+__expf(-rk[h*64+v]));

#pragma unroll 1
  for (int ss=0; ss<32; ss++){
    const int t = tg*32 + ss;
    const int token = b*T_ + c*L_ + t;
    const float* mrow = md + ((size_t)blk*L_ + t)*128;
    float o0=0.f,o1=0.f,o2=0.f,o3=0.f;
#pragma unroll
    for (int f=0;f<16;f+=4){
      float4 m0 = ((const float4*)mrow)[f+0];
      float4 m1 = ((const float4*)mrow)[f+1];
      float4 m2 = ((const float4*)mrow)[f+2];
      float4 m3 = ((const float4*)mrow)[f+3];
      o0 = fmaf(sr[f+0].x,m0.x, fmaf(sr[f+0].y,m0.y, fmaf(sr[f+0].z,m0.z, fmaf(sr[f+0].w,m0.w, o0))));
      o1 = fmaf(sr[f+1].x,m1.x, fmaf(sr[f+1].y,m1.y, fmaf(sr[f+1].z,m1.z, fmaf(sr[f+1].w,m1.w, o1))));
      o2 = fmaf(sr[f+2].x,m2.x, fmaf(sr[f+2].y,m2.y, fmaf(sr[f+2].z,m2.z, fmaf(sr[f+2].w,m2.w, o2))));
      o3 = fmaf(sr[f+3].x,m3.x, fmaf(sr[f+3].y,m3.y, fmaf(sr[f+3].z,m3.z, fmaf(sr[f+3].w,m3.w, o3))));
    }
    float o = ((o0+o1)+(o2+o3)) + mrow[64 + v];
    const float vt = bf2f(vb[(size_t)token*C_ + h*64 + v]);
    const float uv = ratio[(size_t)token*H_ + h];
    const float gv = 1.f + bf2f(delb[(size_t)token*4*C_ + 3*C_ + h*64 + v]);
    y[(size_t)token*C_ + h*64 + v] = f2bf((o*0.125f + vt*uv*sigrk)*gv);
  }
}

extern "C" void kernel_launch(void* const* d_in, const int* in_sizes, int n_in,
                              void* d_out, int out_size, void* d_ws, size_t ws_size,
                              hipStream_t stream)
{
  const float* residual = (const float*)d_in[0];
  const float* x    = (const float*)d_in[1];
  const float* x0   = (const float*)d_in[2];
  const float* dx0  = (const float*)d_in[3];
  const float* Wq   = (const float*)d_in[4];
  const float* Wk   = (const float*)d_in[5];
  const float* Wv   = (const float*)d_in[6];
  const float* Wpr  = (const float*)d_in[7];
  const float* x_q  = (const float*)d_in[8];
  const float* x_k  = (const float*)d_in[9];
  const float* x_v  = (const float*)d_in[10];
  const float* v0   = (const float*)d_in[11];
  const float* w0   = (const float*)d_in[12];
  const float* a0   = (const float*)d_in[13];
  const float* miss = (const float*)d_in[14];
  const float* rk   = (const float*)d_in[15];
  float* out = (float*)d_out;

  char* ws = (char*)d_ws;
  const size_t MB = (size_t)1 << 20;
  // phase A (pre-scan):
  float*    q_m    = (float*)(ws + 0*MB);      // [0,64): q,k,v,vf f32 (live thru mdp)
  float*    k_m    = (float*)(ws + 16*MB);
  float*    v_m    = (float*)(ws + 32*MB);
  float*    vf_m   = (float*)(ws + 48*MB);
  ushort_t* delb   = (ushort_t*)(ws + 64*MB);  // [64,96) bf16 deltas (live thru emit)
  ushort_t* Ab     = (ushort_t*)(ws + 96*MB);  // [96,128): Aq,Ak,Av,Axf (dead after qkvm)
  ushort_t* Xb     = (ushort_t*)(ws + 128*MB); // [128,136) (dead after qkvm)
  ushort_t* Wb     = (ushort_t*)(ws + 136*MB); // [136,144) (dead after qkvm)
  ushort_t* Wpb    = (ushort_t*)(ws + 160*MB); // [160,162) (live to end)
  ushort_t* missT  = (ushort_t*)(ws + 162*MB); // [162,163) (dead after qkvm)
  float*    ratio  = (float*)(ws + 163*MB);    // 256KB
  // phase C (scan onward — overlays only qkvm-dead regions):
  float*    mdbuf  = (float*)(ws + 96*MB);     // [96,128) over Ab (32MB)
  float*    phi    = (float*)(ws + 128*MB);    // [128,136) over Xb
  float*    cc     = (float*)(ws + 136*MB);    // [136,144) over Wb
  float*    sstart = (float*)(ws + 144*MB);    // [144,152) (old g_m space)
  ushort_t* vb     = (ushort_t*)(ws + 152*MB); // [152,160) bf16 v for emit
  ushort_t* yb     = (ushort_t*)(ws + 48*MB);  // over vf_m (emit runs after mdp)

  ushort_t* Aq  = Ab + 0*(size_t)M_*C_;
  ushort_t* Ak  = Ab + 1*(size_t)M_*C_;
  ushort_t* Av  = Ab + 2*(size_t)M_*C_;
  ushort_t* Axf = Ab + 3*(size_t)M_*C_;

  dim3 blk(256);
  prep_all<<<4096 + 5*1024 + 64, blk, 0, stream>>>(
      x, x0, dx0, x_q, x_k, x_v, Wq, Wk, Wv, Wpr, miss,
      Aq, Ak, Av, Axf, Xb, Wb, Wpb, missT);
  qkvm_gemm<<<2048, blk, 0, stream>>>(Ab, Wb, Xb, missT, q_m, delb);
  chunk_mdp_kernel<<<B_*H_*NC_, dim3(768), 0, stream>>>(
      q_m, k_m, v_m, vf_m, x, delb, w0, v0, a0, phi, cc, mdbuf, vb, ratio);
  chunk_state_kernel<<<dim3(4, B_*H_), blk, 0, stream>>>(phi, cc, sstart);
  chunk_emit_kernel<<<B_*H_*NC_, blk, 0, stream>>>(vb, delb, ratio, rk, sstart, mdbuf, yb);
  mfma_gemm<<<dim3(C_/128, M_/128, 1), blk, 0, stream>>>(
      yb, C_, 0, Wpb, C_, 0, out, C_, 0, 0, residual, C_);
}